// Round 8
// baseline (462.987 us; speedup 1.0000x reference)
//
#include <hip/hip_runtime.h>
#include <math.h>

#define BB 1024
#define TT 512
#define CC 41

__device__ __forceinline__ float rlane(float xv, int l) {
    return __int_as_float(__builtin_amdgcn_readlane(__float_as_int(xv), l));
}

__global__ __launch_bounds__(128) void crf_viterbi_kernel(
    const float* __restrict__ x,
    const float* __restrict__ start_t,
    const float* __restrict__ end_t,
    const float* __restrict__ trans,
    int* __restrict__ out)   // harness reads out_size int32 elements
{
    __shared__ unsigned char bp_lds[(TT - 1) * CC];
    __shared__ int tags_lds[TT];
    __shared__ float exAv[2][CC];   // wave A partial best value (double-buffered)
    __shared__ float exBv[2][CC];   // wave B partial best value
    __shared__ int   exBi[2][CC];   // wave B partial best index (global p)

    const int tid  = threadIdx.x;
    const int w    = tid >> 6;              // 0 = wave A (p 0..20), 1 = wave B (p 21..40)
    const int lane = tid & 63;
    const bool active = lane < CC;
    const int c = active ? lane : (CC - 1); // clamp for safe loads

    const int p0 = w ? 21 : 0;
    const int np = w ? 20 : 21;

    // my p-range's transition rows, column c (coalesced: lanes contiguous per p)
    float trans_reg[21];
    for (int p = 0; p < np; ++p) trans_reg[p] = trans[(p0 + p) * CC + c];

    const float* xb = x + (size_t)blockIdx.x * TT * CC;

    // t = 0: score0 = start_transitions + x[:,0]   (exact ref op order)
    float myscore = start_t[c] + xb[c];

    // 2-deep emit prefetch pipeline
    float emit_cur = xb[1 * CC + c];
    float emit_nxt = xb[2 * CC + c];

    for (int t = 1; t < TT; ++t) {
        const int buf = t & 1;
        const int tf = (t + 2 < TT) ? (t + 2) : (TT - 1);
        const float emit_fut = xb[(size_t)tf * CC + c];

        // Partial candidates over my p-range. Scores broadcast via readlane
        // (both waves hold the full combined score vector from last step).
        // Exact ref op order: (score + trans) + emit.
        float v[21]; int ix[21];
        if (w == 0) {
            #pragma unroll
            for (int p = 0; p < 21; ++p) {
                const float sp = rlane(myscore, p);
                v[p]  = (sp + trans_reg[p]) + emit_cur;
                ix[p] = p;
            }
        } else {
            #pragma unroll
            for (int p = 0; p < 20; ++p) {
                const float sp = rlane(myscore, 21 + p);
                v[p]  = (sp + trans_reg[p]) + emit_cur;
                ix[p] = 21 + p;
            }
            v[20] = -INFINITY;   // pad: never selected (finite data)
            ix[20] = 63;
        }

        // Segment tree over 21 contiguous slots; keep-left on ties ==
        // first-occurrence argmax within the half.
#define COMBINE(i, j) if (v[(j)] > v[(i)]) { v[(i)] = v[(j)]; ix[(i)] = ix[(j)]; }
        #pragma unroll
        for (int i = 0; i < 10; ++i) { COMBINE(2 * i, 2 * i + 1) }
        #pragma unroll
        for (int i = 0; i < 5; ++i)  { COMBINE(4 * i, 4 * i + 2) }
        COMBINE(0, 4) COMBINE(8, 12) COMBINE(16, 20)
        COMBINE(0, 8)
        COMBINE(0, 16)
#undef COMBINE

        // Exchange partials (double-buffered slot, ONE barrier per step).
        if (active) {
            if (w == 0) { exAv[buf][lane] = v[0]; }
            else        { exBv[buf][lane] = v[0]; exBi[buf][lane] = ix[0]; }
        }
        __syncthreads();

        float va, vb; int bi;
        if (w == 0) { va = v[0];         vb = exBv[buf][c]; bi = exBi[buf][c]; }
        else        { va = exAv[buf][c]; vb = v[0];         bi = ix[0]; }

        // A's indices all < B's indices -> keep A on tie == first occurrence.
        myscore = (vb > va) ? vb : va;

        if (w == 0 && active) {
            const int bp = (vb > va) ? bi : ix[0];
            bp_lds[(t - 1) * CC + lane] = (unsigned char)bp;
        }

        emit_cur = emit_nxt;
        emit_nxt = emit_fut;
    }

    // final = score + end_transitions   (exact ref op order)
    const float fin = myscore + end_t[c];

    // Final argmax (first occurrence) — wave-local readlane scan.
    float bestv = rlane(fin, 0);
    int tag = 0;
    #pragma unroll
    for (int i = 1; i < CC; ++i) {
        const float vi = rlane(fin, i);
        if (vi > bestv) { bestv = vi; tag = i; }
    }

    __syncthreads();   // bp_lds writes visible to tid 0

    if (tid == 0) {
        tags_lds[TT - 1] = tag;
        int tg = tag;
        for (int t = TT - 1; t >= 1; --t) {
            tg = (int)bp_lds[(t - 1) * CC + tg];
            tags_lds[t - 1] = tg;
        }
    }
    __syncthreads();

    // coalesced output write: one int32 per tag
    int* ob = out + (size_t)blockIdx.x * TT;
    for (int i = tid; i < TT; i += 128) ob[i] = tags_lds[i];
}

extern "C" void kernel_launch(void* const* d_in, const int* in_sizes, int n_in,
                              void* d_out, int out_size, void* d_ws, size_t ws_size,
                              hipStream_t stream) {
    (void)in_sizes; (void)n_in; (void)d_ws; (void)ws_size; (void)out_size;
    const float* x       = (const float*)d_in[0];
    const float* start_t = (const float*)d_in[1];
    const float* end_t   = (const float*)d_in[2];
    const float* trans   = (const float*)d_in[3];
    int* out = (int*)d_out;

    crf_viterbi_kernel<<<dim3(BB), dim3(128), 0, stream>>>(x, start_t, end_t, trans, out);
}

// Round 9
// 329.871 us; speedup vs baseline: 1.4035x; 1.4035x over previous
//
#include <hip/hip_runtime.h>

#define BB 1024
#define TT 512
#define CC 41

__device__ __forceinline__ float rlanef(float xv, int l) {
    return __int_as_float(__builtin_amdgcn_readlane(__float_as_int(xv), l));
}

__global__ __launch_bounds__(64) void crf_viterbi_kernel(
    const float* __restrict__ x,
    const float* __restrict__ start_t,
    const float* __restrict__ end_t,
    const float* __restrict__ trans,
    int* __restrict__ out)   // harness reads out_size int32 elements
{
    __shared__ unsigned char bp_lds[(TT - 1) * CC];
    __shared__ int tags_lds[TT];

    const int lane = threadIdx.x;
    const bool active = lane < CC;
    const int c = active ? lane : (CC - 1);   // clamp for safe loads

    // trans column c in registers (coalesced: lanes contiguous per p)
    float trans_reg[CC];
    #pragma unroll
    for (int p = 0; p < CC; ++p) trans_reg[p] = trans[p * CC + c];

    const float* xb = x + (size_t)blockIdx.x * TT * CC;

    // t = 0: score0 = start_transitions + x[:,0]   (exact ref op order)
    float myscore = start_t[c] + xb[c];

    // 2-deep emit prefetch pipeline
    float emit_cur = xb[1 * CC + c];
    float emit_nxt = xb[2 * CC + c];

    // Segment anchor maps: A[k][c] = tag at time 64k for the best path that
    // ends at tag c at time 64(k+1)  (k=7: ends at time 511).
    int A[8];

    #pragma unroll
    for (int k = 0; k < 8; ++k) {
        int anchor = lane;                 // identity map at segment start
        const int nj = (k < 7) ? 64 : 63;  // rows 64k .. 64k+nj-1 (<=510)
        #pragma unroll 2
        for (int j = 0; j < nj; ++j) {
            const int t = 64 * k + j + 1;  // t = 1..511
            const int tf = (t + 2 < TT) ? (t + 2) : (TT - 1);
            const float emit_fut = xb[(size_t)tf * CC + c];

            // Broadcast prev scores via readlane; exact ref op order:
            // (score + trans) + emit. All 41 candidates independent.
            float v[CC];
            #pragma unroll
            for (int p = 0; p < CC; ++p) {
                const float sp = rlanef(myscore, p);
                v[p] = (sp + trans_reg[p]) + emit_cur;
            }

            // Value max: depth-6 fmax tree (pure selection -> exact max value).
            float w0[21];
            #pragma unroll
            for (int i = 0; i < 20; ++i) w0[i] = fmaxf(v[2 * i], v[2 * i + 1]);
            w0[20] = v[40];
            float w1[11];
            #pragma unroll
            for (int i = 0; i < 10; ++i) w1[i] = fmaxf(w0[2 * i], w0[2 * i + 1]);
            w1[10] = w0[20];
            float w2[6];
            #pragma unroll
            for (int i = 0; i < 5; ++i) w2[i] = fmaxf(w1[2 * i], w1[2 * i + 1]);
            w2[5] = w1[10];
            float w3a = fmaxf(w2[0], w2[1]);
            float w3b = fmaxf(w2[2], w2[3]);
            float w3c = fmaxf(w2[4], w2[5]);
            const float m = fmaxf(fmaxf(w3a, w3b), w3c);

            // Backpointer: first p with v[p] == m (ties: smallest p ==
            // jnp.argmax first-occurrence; +-0 compare equal; no NaNs).
            // Serial cndmask chain is OFF the score critical path.
            int bp = 40;
            #pragma unroll
            for (int p = 39; p >= 0; --p) bp = (v[p] == m) ? p : bp;

            myscore = m;
            if (active) bp_lds[(t - 1) * CC + lane] = (unsigned char)bp;

            // Compose anchor: anchor_new[c] = anchor_old[bp[c]]
            anchor = __builtin_amdgcn_ds_bpermute(bp << 2, anchor);

            emit_cur = emit_nxt;
            emit_nxt = emit_fut;
        }
        A[k] = anchor;
    }

    // final = score + end_transitions   (exact ref op order)
    const float fin = myscore + end_t[c];

    // Final argmax over tags (first occurrence), uniform via readlane scan.
    float bestv = rlanef(fin, 0);
    int tag = 0;
    #pragma unroll
    for (int i = 1; i < CC; ++i) {
        const float vi = rlanef(fin, i);
        if (vi > bestv) { bestv = vi; tag = i; }
    }

    // Segment-boundary tags: bnd[k] = tag at time 64k.
    int bnd[9];
    bnd[8] = tag;   // tag at time 511 (segment 7's "end")
    #pragma unroll
    for (int k = 7; k >= 0; --k)
        bnd[k] = __builtin_amdgcn_readlane(A[k], bnd[k + 1]);

    __syncthreads();   // drain bp_lds writes before the walk

    // Parallel backtrack: lane k (0..7) walks segment k's rows top-down.
    // tag_r = bp[r][tag_{r+1}];  8 independent chains pipeline LDS latency.
    {
        int tg = bnd[1];
        #pragma unroll
        for (int k = 1; k < 8; ++k) if (lane == k) tg = bnd[k + 1];

        if (lane == 0) tags_lds[TT - 1] = bnd[8];
        if (lane < 8) {
            const int rbase = 64 * lane;
            const int nj = (lane < 7) ? 64 : 63;
            for (int j = nj - 1; j >= 0; --j) {
                tg = (int)bp_lds[(rbase + j) * CC + tg];
                tags_lds[rbase + j] = tg;
            }
        }
    }
    __syncthreads();

    // coalesced output write: one int32 per tag
    int* ob = out + (size_t)blockIdx.x * TT;
    #pragma unroll
    for (int i = 0; i < TT / 64; ++i) ob[lane + 64 * i] = tags_lds[lane + 64 * i];
}

extern "C" void kernel_launch(void* const* d_in, const int* in_sizes, int n_in,
                              void* d_out, int out_size, void* d_ws, size_t ws_size,
                              hipStream_t stream) {
    (void)in_sizes; (void)n_in; (void)d_ws; (void)ws_size; (void)out_size;
    const float* x       = (const float*)d_in[0];
    const float* start_t = (const float*)d_in[1];
    const float* end_t   = (const float*)d_in[2];
    const float* trans   = (const float*)d_in[3];
    int* out = (int*)d_out;

    crf_viterbi_kernel<<<dim3(BB), dim3(64), 0, stream>>>(x, start_t, end_t, trans, out);
}